// Round 3
// baseline (197.327 us; speedup 1.0000x reference)
//
#include <hip/hip_runtime.h>
#include <stdint.h>

#define B_ROWS 8192
#define H_DIM 1024
#define L_DIM 1024
#define NH 5

typedef short bf16x8 __attribute__((ext_vector_type(8)));
typedef float f32x4 __attribute__((ext_vector_type(4)));

typedef const __attribute__((address_space(1))) unsigned int* gas_uint_ptr;
typedef __attribute__((address_space(3))) unsigned int* las_uint_ptr;

__device__ __forceinline__ unsigned short f2bf(float f) {
  union { float f; unsigned int u; } v; v.f = f;
  return (unsigned short)((v.u + 0x7FFFu + ((v.u >> 16) & 1u)) >> 16);
}

__device__ __forceinline__ void load_lds16(const void* gsrc, void* ldst) {
  __builtin_amdgcn_global_load_lds((gas_uint_ptr)(uintptr_t)gsrc,
                                   (las_uint_ptr)(uintptr_t)ldst, 16, 0, 0);
}

// ---- kernel 1: fused prep ----
// blocks [0, 8192): per-row — group==5: fill out row with label;
//                   else: convert hidden row fp32->bf16 into Hb, bucket row into rowlist.
// blocks [8192, 13312): W fp32 -> bf16 (5*1024*1024 elems).
__global__ void k_prep(const float* __restrict__ hidden, const float* __restrict__ W,
                       const int* __restrict__ group, const int* __restrict__ labels,
                       int* __restrict__ cnt, int* __restrict__ rowlist,
                       unsigned short* __restrict__ Hb, unsigned short* __restrict__ Wb,
                       float* __restrict__ out) {
  const int blk = blockIdx.x;
  const int t = threadIdx.x;
  if (blk < B_ROWS) {
    int g = group[blk];
    if (g == NH) {
      float v = (float)labels[blk];
      ((float4*)(out + (size_t)blk * L_DIM))[t] = make_float4(v, v, v, v);
    } else {
      float4 h = ((const float4*)(hidden + (size_t)blk * H_DIM))[t];
      ushort4 o;
      o.x = f2bf(h.x); o.y = f2bf(h.y); o.z = f2bf(h.z); o.w = f2bf(h.w);
      ((ushort4*)(Hb + (size_t)blk * H_DIM))[t] = o;
      if (t == 0) {
        int pos = atomicAdd(&cnt[g], 1);
        rowlist[g * B_ROWS + pos] = blk;
      }
    }
  } else {
    int i = (blk - B_ROWS) * 256 + t;
    float4 w = ((const float4*)W)[i];
    ushort4 o;
    o.x = f2bf(w.x); o.y = f2bf(w.y); o.z = f2bf(w.z); o.w = f2bf(w.w);
    ((ushort4*)Wb)[i] = o;
  }
}

// ---- kernel 2: bucketed bf16 MFMA GEMM, double-buffered LDS, rowlist-indirect A ----
// 128x128 tile, BK=64, 4 waves (2x2), each wave 4x4 frags of 16x16x32.
// LDS XOR-swizzle: chunk column cl holds global column cl ^ (row&7) (bank spread).
// Double buffer: stage kt+1 BEFORE computing kt, so the vmcnt(0) drain at the
// end-of-iteration barrier overlaps the whole MFMA+ds_read phase.
__global__ __launch_bounds__(256, 2)
void k_gemm(const unsigned short* __restrict__ Hb, const unsigned short* __restrict__ Wb,
            const float* __restrict__ bias, const int* __restrict__ cnt,
            const int* __restrict__ rowlist, float* __restrict__ out) {
  const int head = blockIdx.z;
  const int cntg = cnt[head];
  const int rowbase = blockIdx.y * 128;
  if (rowbase >= cntg) return;
  const int n0 = blockIdx.x * 128;

  __shared__ __align__(16) unsigned short As[2][128 * 64];
  __shared__ __align__(16) unsigned short Bs[2][128 * 64];

  const int t = threadIdx.x;
  const int wave = t >> 6, lane = t & 63;
  const int quad = lane >> 4, c16 = lane & 15;
  const int wm = (wave & 1) * 64, wn = (wave >> 1) * 64;

  const unsigned short* Wg = Wb + (size_t)head * L_DIM * H_DIM;
  const int* rl = rowlist + head * B_ROWS;

  // precompute per-thread staging sources (loop-invariant; +kt per iteration)
  const unsigned short* srcA[4];
  const unsigned short* srcB[4];
  int ldso[4];
#pragma unroll
  for (int p = 0; p < 4; p++) {
    int c = p * 256 + t;                  // 16B chunk id 0..1023
    int row = c >> 3;
    int ks = ((c & 7) ^ (row & 7)) * 8;   // XOR-swizzled source column (shorts)
    int idx = rowbase + row;
    idx = idx < cntg ? idx : cntg - 1;    // clamp into valid rowlist entries
    int rA = rl[idx];
    srcA[p] = Hb + (size_t)rA * H_DIM + ks;
    srcB[p] = Wg + (size_t)(n0 + row) * H_DIM + ks;
    ldso[p] = c * 8;                      // lane-linear LDS dst (shorts)
  }

  f32x4 acc[4][4] = {};

  // prologue: stage tile 0
#pragma unroll
  for (int p = 0; p < 4; p++) {
    load_lds16(srcA[p], &As[0][ldso[p]]);
    load_lds16(srcB[p], &Bs[0][ldso[p]]);
  }
  __syncthreads();

  for (int kt = 0; kt < H_DIM; kt += 64) {
    const int cur = (kt >> 6) & 1;
    if (kt + 64 < H_DIM) {
      const int nxt = cur ^ 1;
#pragma unroll
      for (int p = 0; p < 4; p++) {
        load_lds16(srcA[p] + kt + 64, &As[nxt][ldso[p]]);
        load_lds16(srcB[p] + kt + 64, &Bs[nxt][ldso[p]]);
      }
    }
#pragma unroll
    for (int kk = 0; kk < 64; kk += 32) {
      bf16x8 af[4], bf[4];
      const int sw = c16 & 7;             // row&7 == c16&7 for all frag rows
      const int colb = (kk >> 4) << 1;    // kk=0 -> chunks 0..3, kk=32 -> 4..7
#pragma unroll
      for (int i = 0; i < 4; i++) {
        int row = wm + i * 16 + c16;
        int cl = (colb + quad) ^ sw;
        af[i] = *(const bf16x8*)(&As[cur][row * 64 + cl * 8]);
      }
#pragma unroll
      for (int j = 0; j < 4; j++) {
        int row = wn + j * 16 + c16;
        int cl = (colb + quad) ^ sw;
        bf[j] = *(const bf16x8*)(&Bs[cur][row * 64 + cl * 8]);
      }
#pragma unroll
      for (int i = 0; i < 4; i++)
#pragma unroll
        for (int j = 0; j < 4; j++)
          acc[i][j] = __builtin_amdgcn_mfma_f32_16x16x32_bf16(af[i], bf[j], acc[i][j], 0, 0, 0);
    }
    __syncthreads();   // drains prefetch vmcnt (overlapped with compute above)
  }

  // epilogue: C/D layout col=lane&15, row=quad*4+reg; scatter through rowlist, add bias
#pragma unroll
  for (int i = 0; i < 4; i++) {
    int rloc0 = wm + i * 16 + quad * 4;
#pragma unroll
    for (int r = 0; r < 4; r++) {
      int idx = rloc0 + r;
      if (rowbase + idx < cntg) {
        int orow = rl[rowbase + idx];
        float* orowp = out + (size_t)orow * L_DIM + n0;
#pragma unroll
        for (int j = 0; j < 4; j++) {
          int n = wn + j * 16 + c16;
          orowp[n] = acc[i][j][r] + bias[head * L_DIM + n0 + n];
        }
      }
    }
  }
}

extern "C" void kernel_launch(void* const* d_in, const int* in_sizes, int n_in,
                              void* d_out, int out_size, void* d_ws, size_t ws_size,
                              hipStream_t stream) {
  const float* hidden = (const float*)d_in[0];
  const float* W      = (const float*)d_in[1];
  const float* bias   = (const float*)d_in[2];
  const int* group    = (const int*)d_in[3];
  const int* labels   = (const int*)d_in[4];
  float* out = (float*)d_out;

  // ws layout: [cnt 64B][rowlist 5*8192*4B @256][Wb bf16 @256KB][Hb bf16 after Wb]
  char* ws = (char*)d_ws;
  int* cnt = (int*)ws;
  int* rowlist = (int*)(ws + 256);
  unsigned short* Wb = (unsigned short*)(ws + (1 << 18));
  unsigned short* Hb = (unsigned short*)(ws + (1 << 18) + (size_t)NH * L_DIM * H_DIM * 2);

  hipMemsetAsync(cnt, 0, 64, stream);
  k_prep<<<B_ROWS + NH * L_DIM * H_DIM / 1024, 256, 0, stream>>>(
      hidden, W, group, labels, cnt, rowlist, Hb, Wb, out);
  k_gemm<<<dim3(L_DIM / 128, B_ROWS / 128, NH), 256, 0, stream>>>(Hb, Wb, bias, cnt, rowlist, out);
}

// Round 4
// 129.515 us; speedup vs baseline: 1.5236x; 1.5236x over previous
//
#include <hip/hip_runtime.h>
#include <stdint.h>

#define B_ROWS 8192
#define H_DIM 1024
#define L_DIM 1024
#define NH 5

typedef short bf16x8 __attribute__((ext_vector_type(8)));
typedef float f32x4 __attribute__((ext_vector_type(4)));

typedef const __attribute__((address_space(1))) unsigned int* gas_uint_ptr;
typedef __attribute__((address_space(3))) unsigned int* las_uint_ptr;

__device__ __forceinline__ unsigned short f2bf(float f) {
  union { float f; unsigned int u; } v; v.f = f;
  return (unsigned short)((v.u + 0x7FFFu + ((v.u >> 16) & 1u)) >> 16);
}

__device__ __forceinline__ void load_lds16(const void* gsrc, void* ldst) {
  __builtin_amdgcn_global_load_lds((gas_uint_ptr)(uintptr_t)gsrc,
                                   (las_uint_ptr)(uintptr_t)ldst, 16, 0, 0);
}

// ---- kernel 1: bucket rows by group (LDS-aggregated: 5 atomics per block,
// not 1 per row — same-cache-line atomic serialization killed round 3) ----
__global__ void k_bucket(const int* __restrict__ group, int* __restrict__ cnt,
                         int* __restrict__ rowlist) {
  __shared__ int lcnt[NH];
  __shared__ int lbase[NH];
  int t = threadIdx.x;
  if (t < NH) lcnt[t] = 0;
  __syncthreads();
  int b = blockIdx.x * 256 + t;
  int g = group[b];
  int lpos = -1;
  if (g < NH) lpos = atomicAdd(&lcnt[g], 1);
  __syncthreads();
  if (t < NH) lbase[t] = atomicAdd(&cnt[t], lcnt[t]);
  __syncthreads();
  if (g < NH) rowlist[g * B_ROWS + lbase[g] + lpos] = b;
}

// ---- kernel 2: fused streaming convert ----
// blocks [0,512):    W fp32->bf16, grid-stride, 10 float4/thread (full ILP)
// blocks [512,1536): 8 rows/block; group prefetched for all 8 rows, then
//                    per row: g==5 -> fill out with label, else hidden->bf16 Hb
__global__ void k_conv(const float* __restrict__ hidden, const float* __restrict__ W,
                       const int* __restrict__ group, const int* __restrict__ labels,
                       unsigned short* __restrict__ Hb, unsigned short* __restrict__ Wb,
                       float* __restrict__ out) {
  const int blk = blockIdx.x;
  const int t = threadIdx.x;
  if (blk < 512) {
    const float4* src = (const float4*)W;
    ushort4* dst = (ushort4*)Wb;
#pragma unroll
    for (int i = 0; i < 10; i++) {
      int idx = (i * 512 + blk) * 256 + t;   // 512*256*10 = 1,310,720 float4 = all of W
      float4 w = src[idx];
      ushort4 o;
      o.x = f2bf(w.x); o.y = f2bf(w.y); o.z = f2bf(w.z); o.w = f2bf(w.w);
      dst[idx] = o;
    }
  } else {
    const int rb = (blk - 512) * 8;
    int gs[8];
#pragma unroll
    for (int r = 0; r < 8; r++) gs[r] = group[rb + r];   // independent loads up front
#pragma unroll
    for (int r = 0; r < 8; r++) {
      int row = rb + r;
      if (gs[r] == NH) {
        float v = (float)labels[row];
        ((float4*)(out + (size_t)row * L_DIM))[t] = make_float4(v, v, v, v);
      } else {
        float4 h = ((const float4*)(hidden + (size_t)row * H_DIM))[t];
        ushort4 o;
        o.x = f2bf(h.x); o.y = f2bf(h.y); o.z = f2bf(h.z); o.w = f2bf(h.w);
        ((ushort4*)(Hb + (size_t)row * H_DIM))[t] = o;
      }
    }
  }
}

// ---- kernel 3: bucketed bf16 MFMA GEMM, double-buffered LDS, rowlist-indirect A ----
// 128x128 tile, BK=64, 4 waves (2x2), each wave 4x4 frags of 16x16x32.
// LDS XOR-swizzle: chunk column cl holds global column cl ^ (row&7) (bank spread).
// Double buffer: stage kt+1 BEFORE computing kt, so the vmcnt(0) drain at the
// end-of-iteration barrier overlaps the whole MFMA+ds_read phase.
__global__ __launch_bounds__(256, 2)
void k_gemm(const unsigned short* __restrict__ Hb, const unsigned short* __restrict__ Wb,
            const float* __restrict__ bias, const int* __restrict__ cnt,
            const int* __restrict__ rowlist, float* __restrict__ out) {
  const int head = blockIdx.z;
  const int cntg = cnt[head];
  const int rowbase = blockIdx.y * 128;
  if (rowbase >= cntg) return;
  const int n0 = blockIdx.x * 128;

  __shared__ __align__(16) unsigned short As[2][128 * 64];
  __shared__ __align__(16) unsigned short Bs[2][128 * 64];

  const int t = threadIdx.x;
  const int wave = t >> 6, lane = t & 63;
  const int quad = lane >> 4, c16 = lane & 15;
  const int wm = (wave & 1) * 64, wn = (wave >> 1) * 64;

  const unsigned short* Wg = Wb + (size_t)head * L_DIM * H_DIM;
  const int* rl = rowlist + head * B_ROWS;

  // precompute per-thread staging sources (loop-invariant; +kt per iteration)
  const unsigned short* srcA[4];
  const unsigned short* srcB[4];
  int ldso[4];
#pragma unroll
  for (int p = 0; p < 4; p++) {
    int c = p * 256 + t;                  // 16B chunk id 0..1023
    int row = c >> 3;
    int ks = ((c & 7) ^ (row & 7)) * 8;   // XOR-swizzled source column (shorts)
    int idx = rowbase + row;
    idx = idx < cntg ? idx : cntg - 1;    // clamp into valid rowlist entries
    int rA = rl[idx];
    srcA[p] = Hb + (size_t)rA * H_DIM + ks;
    srcB[p] = Wg + (size_t)(n0 + row) * H_DIM + ks;
    ldso[p] = c * 8;                      // lane-linear LDS dst (shorts)
  }

  f32x4 acc[4][4] = {};

  // prologue: stage tile 0
#pragma unroll
  for (int p = 0; p < 4; p++) {
    load_lds16(srcA[p], &As[0][ldso[p]]);
    load_lds16(srcB[p], &Bs[0][ldso[p]]);
  }
  __syncthreads();

  for (int kt = 0; kt < H_DIM; kt += 64) {
    const int cur = (kt >> 6) & 1;
    if (kt + 64 < H_DIM) {
      const int nxt = cur ^ 1;
#pragma unroll
      for (int p = 0; p < 4; p++) {
        load_lds16(srcA[p] + kt + 64, &As[nxt][ldso[p]]);
        load_lds16(srcB[p] + kt + 64, &Bs[nxt][ldso[p]]);
      }
    }
#pragma unroll
    for (int kk = 0; kk < 64; kk += 32) {
      bf16x8 af[4], bf[4];
      const int sw = c16 & 7;             // row&7 == c16&7 for all frag rows
      const int colb = (kk >> 4) << 1;    // kk=0 -> chunks 0..3, kk=32 -> 4..7
#pragma unroll
      for (int i = 0; i < 4; i++) {
        int row = wm + i * 16 + c16;
        int cl = (colb + quad) ^ sw;
        af[i] = *(const bf16x8*)(&As[cur][row * 64 + cl * 8]);
      }
#pragma unroll
      for (int j = 0; j < 4; j++) {
        int row = wn + j * 16 + c16;
        int cl = (colb + quad) ^ sw;
        bf[j] = *(const bf16x8*)(&Bs[cur][row * 64 + cl * 8]);
      }
#pragma unroll
      for (int i = 0; i < 4; i++)
#pragma unroll
        for (int j = 0; j < 4; j++)
          acc[i][j] = __builtin_amdgcn_mfma_f32_16x16x32_bf16(af[i], bf[j], acc[i][j], 0, 0, 0);
    }
    __syncthreads();   // drains prefetch vmcnt (overlapped with compute above)
  }

  // epilogue: C/D layout col=lane&15, row=quad*4+reg; scatter through rowlist, add bias
#pragma unroll
  for (int i = 0; i < 4; i++) {
    int rloc0 = wm + i * 16 + quad * 4;
#pragma unroll
    for (int r = 0; r < 4; r++) {
      int idx = rloc0 + r;
      if (rowbase + idx < cntg) {
        int orow = rl[rowbase + idx];
        float* orowp = out + (size_t)orow * L_DIM + n0;
#pragma unroll
        for (int j = 0; j < 4; j++) {
          int n = wn + j * 16 + c16;
          orowp[n] = acc[i][j][r] + bias[head * L_DIM + n0 + n];
        }
      }
    }
  }
}

extern "C" void kernel_launch(void* const* d_in, const int* in_sizes, int n_in,
                              void* d_out, int out_size, void* d_ws, size_t ws_size,
                              hipStream_t stream) {
  const float* hidden = (const float*)d_in[0];
  const float* W      = (const float*)d_in[1];
  const float* bias   = (const float*)d_in[2];
  const int* group    = (const int*)d_in[3];
  const int* labels   = (const int*)d_in[4];
  float* out = (float*)d_out;

  // ws layout: [cnt 64B][rowlist 5*8192*4B @256][Wb bf16 @256KB][Hb bf16 after Wb]
  char* ws = (char*)d_ws;
  int* cnt = (int*)ws;
  int* rowlist = (int*)(ws + 256);
  unsigned short* Wb = (unsigned short*)(ws + (1 << 18));
  unsigned short* Hb = (unsigned short*)(ws + (1 << 18) + (size_t)NH * L_DIM * H_DIM * 2);

  hipMemsetAsync(cnt, 0, 64, stream);
  k_bucket<<<B_ROWS / 256, 256, 0, stream>>>(group, cnt, rowlist);
  k_conv<<<512 + B_ROWS / 8, 256, 0, stream>>>(hidden, W, group, labels, Hb, Wb, out);
  k_gemm<<<dim3(L_DIM / 128, B_ROWS / 128, NH), 256, 0, stream>>>(Hb, Wb, bias, cnt, rowlist, out);
}